// Round 14
// baseline (166.036 us; speedup 1.0000x reference)
//
#include <hip/hip_runtime.h>
#include <stdint.h>

#define N_NODES 50000
#define N_EDGES 600000
#define M_PAD   50048   // padded rows for GEMM tiles (multiple of 64)
#define NXCD    8
#define REG_SZ  6250    // N_NODES / NXCD : dst-region per XCD
#define CAP     48      // slots per node; deg ~ Poisson(12), P(>48) ~ 1e-17
#define ESLICE  2048    // edges per block-slice in fillcap
#define NSLICE  293     // ceil(600000/2048)
#define FILL_BLKS (NSLICE * NXCD * 2)   // 4688 (both relations)

typedef __bf16 bf16x8 __attribute__((ext_vector_type(8)));
typedef float  f32x4  __attribute__((ext_vector_type(4)));
typedef float  vf4    __attribute__((ext_vector_type(4)));   // clang vector: NT-load ok
typedef unsigned vu2  __attribute__((ext_vector_type(2)));   // clang vector: NT-store ok

__device__ __forceinline__ unsigned short f2bf(float f) {
  union { float f; unsigned u; } v; v.f = f;
  unsigned r = v.u + 0x7FFF + ((v.u >> 16) & 1);  // round-to-nearest-even
  return (unsigned short)(r >> 16);
}

__device__ __forceinline__ unsigned cvt_pk_bf16(float lo, float hi) {
  unsigned r;
  asm("v_cvt_pk_bf16_f32 %0, %1, %2" : "=v"(r) : "v"(lo), "v"(hi));
  return r;
}

// Phase 1 (single dispatch):
//  [0, 4688)        fillcap: CSR build, fixed-capacity slots, ONE atomic/edge.
//                   XCD-local region filter (xcd = blockIdx.x & 7).
//  [4688, 10938)    convx: f32 x -> bf16 xb.
//  [10938, 11514)   buildB: pack W into B [n=128][k=1152] bf16.
// All streaming-once traffic (ei, x, W reads; xb, Bm stores) is NON-TEMPORAL so
// it doesn't evict the scatter's csr/cnt lines from L2 (R12: 41MB excess
// writeback attributed to L2 pollution by these streams).
__global__ void phase1_kernel(const int* __restrict__ ei1, const int* __restrict__ ei2,
                              int* __restrict__ cnt1, int* __restrict__ cnt2,
                              unsigned short* __restrict__ csr1, unsigned short* __restrict__ csr2,
                              const float* __restrict__ x, unsigned short* __restrict__ xb,
                              const float* __restrict__ W1a, const float* __restrict__ W2a,
                              const float* __restrict__ W1b, const float* __restrict__ W2b,
                              unsigned short* __restrict__ Bm) {
  int b = blockIdx.x;
  if (b < FILL_BLKS) {
    int region = b & (NXCD - 1);                 // dispatch round-robin -> XCD id
    int sid = b >> 3;                            // 0..585
    int rel = (sid >= NSLICE);
    int slice = rel ? sid - NSLICE : sid;
    const int* ei = rel ? ei2 : ei1;
    int* cnt = rel ? cnt2 : cnt1;
    unsigned short* csr = rel ? csr2 : csr1;
    int lo = region * REG_SZ;
    int base = slice * ESLICE + threadIdx.x;
    #pragma unroll
    for (int k = 0; k < ESLICE / 256; ++k) {
      int i = base + k * 256;
      if (i < N_EDGES) {
        int d = __builtin_nontemporal_load(ei + N_EDGES + i);   // dst (stream)
        if ((unsigned)(d - lo) < (unsigned)REG_SZ) {
          int sr = __builtin_nontemporal_load(ei + i);          // src (stream)
          int r = atomicAdd(&cnt[d], 1);         // rank = histogram + cursor
          if (r < CAP) csr[d * CAP + r] = (unsigned short)sr;
        }
      }
    }
  } else if (b < 4688 + 6250) {                  // convx: float4 index
    int i = (b - 4688) * 256 + threadIdx.x;
    if (i < N_NODES * 32) {
      vf4 v = __builtin_nontemporal_load((const vf4*)x + i);
      vu2 o;
      o.x = cvt_pk_bf16(v.x, v.y);
      o.y = cvt_pk_bf16(v.z, v.w);
      __builtin_nontemporal_store(o, (vu2*)xb + i);
    }
  } else {                                       // buildB: [n=128][k=1152]
    int i = (b - 10938) * 256 + threadIdx.x;
    if (i < 128 * 1152) {
      int n = i / 1152, k = i % 1152;
      float v;
      if (k < 128)      v = __builtin_nontemporal_load(W1a + n * 128 + k) +
                            __builtin_nontemporal_load(W1b + n * 128 + k);
      else if (k < 640) v = __builtin_nontemporal_load(W2a + n * 512 + (k - 128));
      else              v = __builtin_nontemporal_load(W2b + n * 512 + (k - 640));
      unsigned short o = f2bf(v);
      __builtin_nontemporal_store(o, Bm + i);
    }
  }
}

// One wave per node, full wave per edge, EIGHT edges in flight (MLP=8).
// Lane owns channels {2l,2l+1}; reduction fully lane-local. deg from cnt[];
// edge list at csr[wid*CAP ...] (ushort src ids). grid.y selects relation.
__global__ void aggregate_kernel(const unsigned short* __restrict__ xb,
                                 const unsigned short* __restrict__ csr1,
                                 const int* __restrict__ cnt1,
                                 unsigned short* __restrict__ sa,
                                 const unsigned short* __restrict__ csr2,
                                 const int* __restrict__ cnt2,
                                 unsigned short* __restrict__ sb) {
  const unsigned short* csr = blockIdx.y ? csr2 : csr1;
  const int* cnt = blockIdx.y ? cnt2 : cnt1;
  unsigned short* s = blockIdx.y ? sb : sa;
  int wid = blockIdx.x * 4 + (threadIdx.x >> 6);
  int lane = threadIdx.x & 63;
  if (wid >= N_NODES) return;
  int deg = cnt[wid];
  if (deg > CAP) deg = CAP;
  unsigned* row = (unsigned*)(s + (size_t)wid * 512) + lane;
  if (deg == 0) {                              // empty segment: all reducers 0
    row[0] = 0u; row[64] = 0u; row[128] = 0u; row[192] = 0u;
    return;
  }
  int beg = wid * CAP, end = beg + deg;

  const unsigned* xl = (const unsigned*)xb + lane;   // lane-fixed base

  float s0 = 0.f, s1v = 0.f;
  float mx0 = -3.0e38f, mx1 = -3.0e38f;
  float mn0 = 3.0e38f, mn1 = 3.0e38f;

  int e = beg;
  int i0 = csr[e];
  int i1 = (e + 1 < end) ? csr[e + 1] : i0;
  int i2 = (e + 2 < end) ? csr[e + 2] : i0;
  int i3 = (e + 3 < end) ? csr[e + 3] : i0;
  int i4 = (e + 4 < end) ? csr[e + 4] : i0;
  int i5 = (e + 5 < end) ? csr[e + 5] : i0;
  int i6 = (e + 6 < end) ? csr[e + 6] : i0;
  int i7 = (e + 7 < end) ? csr[e + 7] : i0;

  while (e + 7 < end) {
    unsigned u0 = xl[(unsigned)i0 << 6];
    unsigned u1 = xl[(unsigned)i1 << 6];
    unsigned u2 = xl[(unsigned)i2 << 6];
    unsigned u3 = xl[(unsigned)i3 << 6];
    unsigned u4 = xl[(unsigned)i4 << 6];
    unsigned u5 = xl[(unsigned)i5 << 6];
    unsigned u6 = xl[(unsigned)i6 << 6];
    unsigned u7 = xl[(unsigned)i7 << 6];
    int en = e + 8;
    i0 = csr[(en     < end) ? en     : beg];
    i1 = csr[(en + 1 < end) ? en + 1 : beg];
    i2 = csr[(en + 2 < end) ? en + 2 : beg];
    i3 = csr[(en + 3 < end) ? en + 3 : beg];
    i4 = csr[(en + 4 < end) ? en + 4 : beg];
    i5 = csr[(en + 5 < end) ? en + 5 : beg];
    i6 = csr[(en + 6 < end) ? en + 6 : beg];
    i7 = csr[(en + 7 < end) ? en + 7 : beg];
    float a0 = __uint_as_float(u0 << 16), a1 = __uint_as_float(u0 & 0xFFFF0000u);
    float b0 = __uint_as_float(u1 << 16), b1 = __uint_as_float(u1 & 0xFFFF0000u);
    float c0 = __uint_as_float(u2 << 16), c1 = __uint_as_float(u2 & 0xFFFF0000u);
    float d0 = __uint_as_float(u3 << 16), d1 = __uint_as_float(u3 & 0xFFFF0000u);
    float e0 = __uint_as_float(u4 << 16), e1 = __uint_as_float(u4 & 0xFFFF0000u);
    float f0 = __uint_as_float(u5 << 16), f1 = __uint_as_float(u5 & 0xFFFF0000u);
    float g0 = __uint_as_float(u6 << 16), g1 = __uint_as_float(u6 & 0xFFFF0000u);
    float h0 = __uint_as_float(u7 << 16), h1 = __uint_as_float(u7 & 0xFFFF0000u);
    s0  += ((a0 + b0) + (c0 + d0)) + ((e0 + f0) + (g0 + h0));
    s1v += ((a1 + b1) + (c1 + d1)) + ((e1 + f1) + (g1 + h1));
    mx0 = fmaxf(fmaxf(fmaxf(a0, b0), c0), fmaxf(fmaxf(fmaxf(d0, e0), f0), fmaxf(fmaxf(g0, h0), mx0)));
    mx1 = fmaxf(fmaxf(fmaxf(a1, b1), c1), fmaxf(fmaxf(fmaxf(d1, e1), f1), fmaxf(fmaxf(g1, h1), mx1)));
    mn0 = fminf(fminf(fminf(a0, b0), c0), fminf(fminf(fminf(d0, e0), f0), fminf(fminf(g0, h0), mn0)));
    mn1 = fminf(fminf(fminf(a1, b1), c1), fminf(fminf(fminf(d1, e1), f1), fminf(fminf(g1, h1), mn1)));
    e = en;
  }
  int rem = end - e;                           // 0..7 ; i0..i7 = csr[e..e+7] (clamped)
  if (rem >= 4) {
    unsigned u0 = xl[(unsigned)i0 << 6];
    unsigned u1 = xl[(unsigned)i1 << 6];
    unsigned u2 = xl[(unsigned)i2 << 6];
    unsigned u3 = xl[(unsigned)i3 << 6];
    float a0 = __uint_as_float(u0 << 16), a1 = __uint_as_float(u0 & 0xFFFF0000u);
    float b0 = __uint_as_float(u1 << 16), b1 = __uint_as_float(u1 & 0xFFFF0000u);
    float c0 = __uint_as_float(u2 << 16), c1 = __uint_as_float(u2 & 0xFFFF0000u);
    float d0 = __uint_as_float(u3 << 16), d1 = __uint_as_float(u3 & 0xFFFF0000u);
    s0  += (a0 + b0) + (c0 + d0);
    s1v += (a1 + b1) + (c1 + d1);
    mx0 = fmaxf(fmaxf(a0, b0), fmaxf(fmaxf(c0, d0), mx0));
    mx1 = fmaxf(fmaxf(a1, b1), fmaxf(fmaxf(c1, d1), mx1));
    mn0 = fminf(fminf(a0, b0), fminf(fminf(c0, d0), mn0));
    mn1 = fminf(fminf(a1, b1), fminf(fminf(c1, d1), mn1));
    i0 = i4; i1 = i5; i2 = i6;
    rem -= 4;
  }
  if (rem >= 2) {
    unsigned u0 = xl[(unsigned)i0 << 6];
    unsigned u1 = xl[(unsigned)i1 << 6];
    float a0 = __uint_as_float(u0 << 16), a1 = __uint_as_float(u0 & 0xFFFF0000u);
    float b0 = __uint_as_float(u1 << 16), b1 = __uint_as_float(u1 & 0xFFFF0000u);
    s0 += a0 + b0;  s1v += a1 + b1;
    mx0 = fmaxf(fmaxf(a0, b0), mx0);  mx1 = fmaxf(fmaxf(a1, b1), mx1);
    mn0 = fminf(fminf(a0, b0), mn0);  mn1 = fminf(fminf(a1, b1), mn1);
    i0 = i2;
    rem -= 2;
  }
  if (rem >= 1) {
    unsigned u0 = xl[(unsigned)i0 << 6];
    float a0 = __uint_as_float(u0 << 16), a1 = __uint_as_float(u0 & 0xFFFF0000u);
    s0 += a0;  s1v += a1;
    mx0 = fmaxf(mx0, a0);  mx1 = fmaxf(mx1, a1);
    mn0 = fminf(mn0, a0);  mn1 = fminf(mn1, a1);
  }

  float inv = 1.0f / (float)deg;
  row[0]   = cvt_pk_bf16(s0 * inv, s1v * inv);
  row[64]  = cvt_pk_bf16(mx0, mx1);
  row[128] = cvt_pk_bf16(mn0, mn1);
  row[192] = cvt_pk_bf16(s0, s1v);
}

__device__ __forceinline__ void gload16(void* lds, const void* g) {
  __builtin_amdgcn_global_load_lds(
      (const __attribute__((address_space(1))) char*)g,
      (__attribute__((address_space(3))) char*)lds, 16, 0, 0);
}

// One block: 64 rows x 128 cols. K=1152 over {xb, s1, s2}. 4 waves 2x2.
// LDS XOR-swizzled per rule #21 (linear dest, pre-swizzled source, swizzled read).
__global__ __launch_bounds__(256) void gemm_ln_kernel(
    const unsigned short* __restrict__ xb, const unsigned short* __restrict__ s1,
    const unsigned short* __restrict__ s2, const unsigned short* __restrict__ Bm,
    const float* __restrict__ gamma, const float* __restrict__ beta,
    float* __restrict__ out) {
  __shared__ __align__(16) unsigned short As[64 * 64];   // [row][k] swizzled
  __shared__ __align__(16) unsigned short Bs[128 * 64];  // [n][k] swizzled
  __shared__ float rsum[64][2];
  __shared__ float rsq[64][2];

  const int t = threadIdx.x;
  const int lane = t & 63;
  const int wid = t >> 6;
  const int wr = wid >> 1, wc = wid & 1;
  const int m0 = blockIdx.x * 64;

  f32x4 acc[2][4];
  #pragma unroll
  for (int i = 0; i < 2; ++i)
    #pragma unroll
    for (int j = 0; j < 4; ++j) acc[i][j] = {0.f, 0.f, 0.f, 0.f};

  for (int kt = 0; kt < 18; ++kt) {
    const unsigned short* aptr; int astride, kloc;
    if (kt < 2)       { aptr = xb; astride = 128; kloc = kt * 64; }
    else if (kt < 10) { aptr = s1; astride = 512; kloc = (kt - 2) * 64; }
    else              { aptr = s2; astride = 512; kloc = (kt - 10) * 64; }

    #pragma unroll
    for (int i = 0; i < 2; ++i) {                 // A: 512 x 16B chunks
      int chunk = i * 256 + t;
      int r = chunk >> 3, c8 = chunk & 7;
      int c8s = c8 ^ (r & 7);                     // pre-swizzled source column
      gload16(As + chunk * 8, aptr + (size_t)(m0 + r) * astride + kloc + c8s * 8);
    }
    #pragma unroll
    for (int i = 0; i < 4; ++i) {                 // B: 1024 x 16B chunks
      int chunk = i * 256 + t;
      int r = chunk >> 3, c8 = chunk & 7;
      int c8s = c8 ^ (r & 7);
      gload16(Bs + chunk * 8, Bm + (size_t)r * 1152 + kt * 64 + c8s * 8);
    }
    __syncthreads();

    #pragma unroll
    for (int kk = 0; kk < 2; ++kk) {
      bf16x8 a[2], b[4];
      int ccb = kk * 4 + (lane >> 4);             // chunk-column base (0..7)
      #pragma unroll
      for (int mf = 0; mf < 2; ++mf) {
        int row = wr * 32 + mf * 16 + (lane & 15);
        int swz = ccb ^ (row & 7);                // swizzled read
        a[mf] = *(const bf16x8*)(As + row * 64 + swz * 8);
      }
      #pragma unroll
      for (int nf = 0; nf < 4; ++nf) {
        int n = wc * 64 + nf * 16 + (lane & 15);
        int swz = ccb ^ (n & 7);
        b[nf] = *(const bf16x8*)(Bs + n * 64 + swz * 8);
      }
      #pragma unroll
      for (int mf = 0; mf < 2; ++mf)
        #pragma unroll
        for (int nf = 0; nf < 4; ++nf)
          acc[mf][nf] = __builtin_amdgcn_mfma_f32_16x16x32_bf16(a[mf], b[nf], acc[mf][nf], 0, 0, 0);
    }
    __syncthreads();
  }

  // epilogue: h = relu(0.5*acc); LayerNorm over 128 cols per row
  float g[4], bta[4];
  #pragma unroll
  for (int nf = 0; nf < 4; ++nf) {
    int n = wc * 64 + nf * 16 + (lane & 15);
    g[nf] = gamma[n]; bta[nf] = beta[n];
  }

  #pragma unroll
  for (int mf = 0; mf < 2; ++mf) {
    #pragma unroll
    for (int r = 0; r < 4; ++r) {
      float ps = 0.f, pq = 0.f;
      #pragma unroll
      for (int nf = 0; nf < 4; ++nf) {
        float v = fmaxf(0.5f * acc[mf][nf][r], 0.0f);
        acc[mf][nf][r] = v;
        ps += v; pq += v * v;
      }
      #pragma unroll
      for (int d = 1; d < 16; d <<= 1) {
        ps += __shfl_xor(ps, d);
        pq += __shfl_xor(pq, d);
      }
      if ((lane & 15) == 0) {
        int m = wr * 32 + mf * 16 + ((lane >> 4) << 2) + r;
        rsum[m][wc] = ps;
        rsq[m][wc] = pq;
      }
    }
  }
  __syncthreads();

  #pragma unroll
  for (int mf = 0; mf < 2; ++mf) {
    #pragma unroll
    for (int r = 0; r < 4; ++r) {
      int m = wr * 32 + mf * 16 + ((lane >> 4) << 2) + r;
      float sum = rsum[m][0] + rsum[m][1];
      float sq  = rsq[m][0] + rsq[m][1];
      float mu = sum * (1.0f / 128.0f);
      float var = fmaxf(sq * (1.0f / 128.0f) - mu * mu, 0.0f);
      float rstd = rsqrtf(var + 1e-5f);
      int mg = m0 + m;
      if (mg < N_NODES) {
        #pragma unroll
        for (int nf = 0; nf < 4; ++nf) {
          int n = wc * 64 + nf * 16 + (lane & 15);
          out[(size_t)mg * 128 + n] = (acc[mf][nf][r] - mu) * rstd * g[nf] + bta[nf];
        }
      }
    }
  }
}

extern "C" void kernel_launch(void* const* d_in, const int* in_sizes, int n_in,
                              void* d_out, int out_size, void* d_ws, size_t ws_size,
                              hipStream_t stream) {
  const float* x    = (const float*)d_in[0];
  const int*   ei1  = (const int*)d_in[1];
  const int*   ei2  = (const int*)d_in[2];
  const float* W1a  = (const float*)d_in[3];
  const float* W2a  = (const float*)d_in[4];
  const float* W1b  = (const float*)d_in[5];
  const float* W2b  = (const float*)d_in[6];
  const float* gamma = (const float*)d_in[7];
  const float* beta  = (const float*)d_in[8];
  float* out = (float*)d_out;

  char* w = (char*)d_ws;
  auto alloc = [&](size_t b) { char* p = w; w += (b + 255) & ~(size_t)255; return p; };
  int* cnt1 = (int*)alloc((size_t)N_NODES * 4);
  int* cnt2 = (int*)alloc((size_t)N_NODES * 4);
  unsigned short* xb = (unsigned short*)alloc((size_t)M_PAD * 128 * 2);
  unsigned short* s1 = (unsigned short*)alloc((size_t)M_PAD * 512 * 2);
  unsigned short* s2 = (unsigned short*)alloc((size_t)M_PAD * 512 * 2);
  unsigned short* Bm = (unsigned short*)alloc((size_t)128 * 1152 * 2);

  // CSR slot arrays live in d_out: 2 * 50000*48*2B = 9.6MB << 25.6MB out buffer.
  unsigned short* csr1 = (unsigned short*)d_out;
  unsigned short* csr2 = csr1 + (size_t)N_NODES * CAP;

  hipMemsetAsync(cnt1, 0, (size_t)2 * N_NODES * 4 + 256, stream);
  phase1_kernel<<<11514, 256, 0, stream>>>(ei1, ei2, cnt1, cnt2, csr1, csr2,
                                           x, xb, W1a, W2a, W1b, W2b, Bm);
  aggregate_kernel<<<dim3(12500, 2), 256, 0, stream>>>(xb, csr1, cnt1, s1, csr2, cnt2, s2);
  gemm_ln_kernel<<<782, 256, 0, stream>>>(xb, s1, s2, Bm, gamma, beta, out);
}

// Round 15
// 155.823 us; speedup vs baseline: 1.0655x; 1.0655x over previous
//
#include <hip/hip_runtime.h>
#include <stdint.h>

#define N_NODES 50000
#define N_EDGES 600000
#define M_PAD   50048   // padded rows for GEMM tiles (multiple of 64)
#define NXCD    8
#define REG_SZ  6250    // N_NODES / NXCD : dst-region per XCD
#define CAP     48      // slots per node; deg ~ Poisson(12), max deg ~ 30
#define ESLICE  2048    // edges per block-slice in fillcap
#define NSLICE  293     // ceil(600000/2048)
#define FILL_BLKS (NSLICE * NXCD * 2)   // 4688 (both relations)

typedef __bf16 bf16x8 __attribute__((ext_vector_type(8)));
typedef float  f32x4  __attribute__((ext_vector_type(4)));

__device__ __forceinline__ unsigned short f2bf(float f) {
  union { float f; unsigned u; } v; v.f = f;
  unsigned r = v.u + 0x7FFF + ((v.u >> 16) & 1);  // round-to-nearest-even
  return (unsigned short)(r >> 16);
}

__device__ __forceinline__ unsigned cvt_pk_bf16(float lo, float hi) {
  unsigned r;
  asm("v_cvt_pk_bf16_f32 %0, %1, %2" : "=v"(r) : "v"(lo), "v"(hi));
  return r;
}

// Phase 1 (single dispatch):
//  [0, 4688)        fillcap: CSR build, fixed-capacity slots, ONE atomic/edge.
//                   XCD-local region filter (xcd = blockIdx.x & 7).
//  [4688, 10938)    convx: f32 x -> bf16 xb.
//  [10938, 11514)   buildB: pack W into B [n=128][k=1152] bf16, deg-fold layout:
//                   k<128: W1a+W1b ; 128-512: W2a[:,0:384] ; 512-896: W2b[:,0:384]
//                   896-1024: W2a[:,384:512] (sum wts) ; 1024-1152: W2b[:,384:512]
__global__ void phase1_kernel(const int* __restrict__ ei1, const int* __restrict__ ei2,
                              int* __restrict__ cnt1, int* __restrict__ cnt2,
                              unsigned short* __restrict__ csr1, unsigned short* __restrict__ csr2,
                              const float* __restrict__ x, unsigned short* __restrict__ xb,
                              const float* __restrict__ W1a, const float* __restrict__ W2a,
                              const float* __restrict__ W1b, const float* __restrict__ W2b,
                              unsigned short* __restrict__ Bm) {
  int b = blockIdx.x;
  if (b < FILL_BLKS) {
    int region = b & (NXCD - 1);                 // dispatch round-robin -> XCD id
    int sid = b >> 3;                            // 0..585
    int rel = (sid >= NSLICE);
    int slice = rel ? sid - NSLICE : sid;
    const int* ei = rel ? ei2 : ei1;
    int* cnt = rel ? cnt2 : cnt1;
    unsigned short* csr = rel ? csr2 : csr1;
    int lo = region * REG_SZ;
    int base = slice * ESLICE + threadIdx.x;
    #pragma unroll
    for (int k = 0; k < ESLICE / 256; ++k) {
      int i = base + k * 256;
      if (i < N_EDGES) {
        int d = ei[N_EDGES + i];                 // dst
        if ((unsigned)(d - lo) < (unsigned)REG_SZ) {
          int r = atomicAdd(&cnt[d], 1);         // rank = histogram + cursor
          if (r < CAP) csr[d * CAP + r] = (unsigned short)ei[i];
        }
      }
    }
  } else if (b < 4688 + 6250) {                  // convx: float4 index
    int i = (b - 4688) * 256 + threadIdx.x;
    if (i < N_NODES * 32) {
      float4 v = ((const float4*)x)[i];
      unsigned lo = cvt_pk_bf16(v.x, v.y);
      unsigned hi = cvt_pk_bf16(v.z, v.w);
      ((uint2*)xb)[i] = make_uint2(lo, hi);
    }
  } else {                                       // buildB: [n=128][k=1152]
    int i = (b - 10938) * 256 + threadIdx.x;
    if (i < 128 * 1152) {
      int n = i / 1152, k = i % 1152;
      float v;
      if (k < 128)       v = W1a[n * 128 + k] + W1b[n * 128 + k];
      else if (k < 512)  v = W2a[n * 512 + (k - 128)];
      else if (k < 896)  v = W2b[n * 512 + (k - 512)];
      else if (k < 1024) v = W2a[n * 512 + 384 + (k - 896)];
      else               v = W2b[n * 512 + 384 + (k - 1024)];
      Bm[i] = f2bf(v);
    }
  }
}

// One wave per node, full wave per edge, EIGHT edges in flight (MLP=8).
// Lane owns channels {2l,2l+1}; reduction fully lane-local. deg from cnt[];
// edge list at csr[wid*CAP ...] (ushort src ids). Output bf16 [N][384] =
// mean|max|min (sum is deg-folded into the GEMM). grid.y selects relation.
__global__ void aggregate_kernel(const unsigned short* __restrict__ xb,
                                 const unsigned short* __restrict__ csr1,
                                 const int* __restrict__ cnt1,
                                 unsigned short* __restrict__ sa,
                                 const unsigned short* __restrict__ csr2,
                                 const int* __restrict__ cnt2,
                                 unsigned short* __restrict__ sb) {
  const unsigned short* csr = blockIdx.y ? csr2 : csr1;
  const int* cnt = blockIdx.y ? cnt2 : cnt1;
  unsigned short* s = blockIdx.y ? sb : sa;
  int wid = blockIdx.x * 4 + (threadIdx.x >> 6);
  int lane = threadIdx.x & 63;
  if (wid >= N_NODES) return;
  int deg = cnt[wid];
  if (deg > CAP) deg = CAP;
  unsigned* row = (unsigned*)(s + (size_t)wid * 384) + lane;
  if (deg == 0) {                              // empty segment: all reducers 0
    row[0] = 0u; row[64] = 0u; row[128] = 0u;
    return;
  }
  int beg = wid * CAP, end = beg + deg;

  const unsigned* xl = (const unsigned*)xb + lane;   // lane-fixed base

  float s0 = 0.f, s1v = 0.f;
  float mx0 = -3.0e38f, mx1 = -3.0e38f;
  float mn0 = 3.0e38f, mn1 = 3.0e38f;

  int e = beg;
  int i0 = csr[e];
  int i1 = (e + 1 < end) ? csr[e + 1] : i0;
  int i2 = (e + 2 < end) ? csr[e + 2] : i0;
  int i3 = (e + 3 < end) ? csr[e + 3] : i0;
  int i4 = (e + 4 < end) ? csr[e + 4] : i0;
  int i5 = (e + 5 < end) ? csr[e + 5] : i0;
  int i6 = (e + 6 < end) ? csr[e + 6] : i0;
  int i7 = (e + 7 < end) ? csr[e + 7] : i0;

  while (e + 7 < end) {
    unsigned u0 = xl[(unsigned)i0 << 6];
    unsigned u1 = xl[(unsigned)i1 << 6];
    unsigned u2 = xl[(unsigned)i2 << 6];
    unsigned u3 = xl[(unsigned)i3 << 6];
    unsigned u4 = xl[(unsigned)i4 << 6];
    unsigned u5 = xl[(unsigned)i5 << 6];
    unsigned u6 = xl[(unsigned)i6 << 6];
    unsigned u7 = xl[(unsigned)i7 << 6];
    int en = e + 8;
    i0 = csr[(en     < end) ? en     : beg];
    i1 = csr[(en + 1 < end) ? en + 1 : beg];
    i2 = csr[(en + 2 < end) ? en + 2 : beg];
    i3 = csr[(en + 3 < end) ? en + 3 : beg];
    i4 = csr[(en + 4 < end) ? en + 4 : beg];
    i5 = csr[(en + 5 < end) ? en + 5 : beg];
    i6 = csr[(en + 6 < end) ? en + 6 : beg];
    i7 = csr[(en + 7 < end) ? en + 7 : beg];
    float a0 = __uint_as_float(u0 << 16), a1 = __uint_as_float(u0 & 0xFFFF0000u);
    float b0 = __uint_as_float(u1 << 16), b1 = __uint_as_float(u1 & 0xFFFF0000u);
    float c0 = __uint_as_float(u2 << 16), c1 = __uint_as_float(u2 & 0xFFFF0000u);
    float d0 = __uint_as_float(u3 << 16), d1 = __uint_as_float(u3 & 0xFFFF0000u);
    float e0 = __uint_as_float(u4 << 16), e1 = __uint_as_float(u4 & 0xFFFF0000u);
    float f0 = __uint_as_float(u5 << 16), f1 = __uint_as_float(u5 & 0xFFFF0000u);
    float g0 = __uint_as_float(u6 << 16), g1 = __uint_as_float(u6 & 0xFFFF0000u);
    float h0 = __uint_as_float(u7 << 16), h1 = __uint_as_float(u7 & 0xFFFF0000u);
    s0  += ((a0 + b0) + (c0 + d0)) + ((e0 + f0) + (g0 + h0));
    s1v += ((a1 + b1) + (c1 + d1)) + ((e1 + f1) + (g1 + h1));
    mx0 = fmaxf(fmaxf(fmaxf(a0, b0), c0), fmaxf(fmaxf(fmaxf(d0, e0), f0), fmaxf(fmaxf(g0, h0), mx0)));
    mx1 = fmaxf(fmaxf(fmaxf(a1, b1), c1), fmaxf(fmaxf(fmaxf(d1, e1), f1), fmaxf(fmaxf(g1, h1), mx1)));
    mn0 = fminf(fminf(fminf(a0, b0), c0), fminf(fminf(fminf(d0, e0), f0), fminf(fminf(g0, h0), mn0)));
    mn1 = fminf(fminf(fminf(a1, b1), c1), fminf(fminf(fminf(d1, e1), f1), fminf(fminf(g1, h1), mn1)));
    e = en;
  }
  int rem = end - e;                           // 0..7 ; i0..i7 = csr[e..e+7] (clamped)
  if (rem >= 4) {
    unsigned u0 = xl[(unsigned)i0 << 6];
    unsigned u1 = xl[(unsigned)i1 << 6];
    unsigned u2 = xl[(unsigned)i2 << 6];
    unsigned u3 = xl[(unsigned)i3 << 6];
    float a0 = __uint_as_float(u0 << 16), a1 = __uint_as_float(u0 & 0xFFFF0000u);
    float b0 = __uint_as_float(u1 << 16), b1 = __uint_as_float(u1 & 0xFFFF0000u);
    float c0 = __uint_as_float(u2 << 16), c1 = __uint_as_float(u2 & 0xFFFF0000u);
    float d0 = __uint_as_float(u3 << 16), d1 = __uint_as_float(u3 & 0xFFFF0000u);
    s0  += (a0 + b0) + (c0 + d0);
    s1v += (a1 + b1) + (c1 + d1);
    mx0 = fmaxf(fmaxf(a0, b0), fmaxf(fmaxf(c0, d0), mx0));
    mx1 = fmaxf(fmaxf(a1, b1), fmaxf(fmaxf(c1, d1), mx1));
    mn0 = fminf(fminf(a0, b0), fminf(fminf(c0, d0), mn0));
    mn1 = fminf(fminf(a1, b1), fminf(fminf(c1, d1), mn1));
    i0 = i4; i1 = i5; i2 = i6;
    rem -= 4;
  }
  if (rem >= 2) {
    unsigned u0 = xl[(unsigned)i0 << 6];
    unsigned u1 = xl[(unsigned)i1 << 6];
    float a0 = __uint_as_float(u0 << 16), a1 = __uint_as_float(u0 & 0xFFFF0000u);
    float b0 = __uint_as_float(u1 << 16), b1 = __uint_as_float(u1 & 0xFFFF0000u);
    s0 += a0 + b0;  s1v += a1 + b1;
    mx0 = fmaxf(fmaxf(a0, b0), mx0);  mx1 = fmaxf(fmaxf(a1, b1), mx1);
    mn0 = fminf(fminf(a0, b0), mn0);  mn1 = fminf(fminf(a1, b1), mn1);
    i0 = i2;
    rem -= 2;
  }
  if (rem >= 1) {
    unsigned u0 = xl[(unsigned)i0 << 6];
    float a0 = __uint_as_float(u0 << 16), a1 = __uint_as_float(u0 & 0xFFFF0000u);
    s0 += a0;  s1v += a1;
    mx0 = fmaxf(mx0, a0);  mx1 = fmaxf(mx1, a1);
    mn0 = fminf(mn0, a0);  mn1 = fminf(mn1, a1);
  }

  float inv = 1.0f / (float)deg;
  row[0]   = cvt_pk_bf16(s0 * inv, s1v * inv);
  row[64]  = cvt_pk_bf16(mx0, mx1);
  row[128] = cvt_pk_bf16(mn0, mn1);
}

__device__ __forceinline__ void gload16(void* lds, const void* g) {
  __builtin_amdgcn_global_load_lds(
      (const __attribute__((address_space(1))) char*)g,
      (__attribute__((address_space(3))) char*)lds, 16, 0, 0);
}

// One block: 64 rows x 128 cols. K = 896 over {xb(128), s1(384), s2(384)}, plus
// DEG-FOLD: for the mean tiles (kt 2,3 rel1 / 8,9 rel2) the A fragment is
// re-scaled per-row by deg and MFMA'd against the sum-weight B columns
// (Bm k in [896,1152)) into the same acc -- replaces the materialized sum
// reducer. LDS XOR-swizzled per rule #21. Fused 0.5*+relu+LayerNorm epilogue.
__global__ __launch_bounds__(256) void gemm_ln_kernel(
    const unsigned short* __restrict__ xb, const unsigned short* __restrict__ s1,
    const unsigned short* __restrict__ s2, const unsigned short* __restrict__ Bm,
    const int* __restrict__ cnt1, const int* __restrict__ cnt2,
    const float* __restrict__ gamma, const float* __restrict__ beta,
    float* __restrict__ out) {
  __shared__ __align__(16) unsigned short As[64 * 64];    // [row][k] swizzled
  __shared__ __align__(16) unsigned short Bs[128 * 64];   // [n][k] swizzled
  __shared__ __align__(16) unsigned short Bs2[128 * 64];  // sum-weight tile
  __shared__ float rsum[64][2];
  __shared__ float rsq[64][2];

  const int t = threadIdx.x;
  const int lane = t & 63;
  const int wid = t >> 6;
  const int wr = wid >> 1, wc = wid & 1;
  const int m0 = blockIdx.x * 64;

  // per-row degrees for the deg-fold (row = m0 + wr*32 + mf*16 + (lane&15))
  float dga[2], dgb[2];
  #pragma unroll
  for (int mf = 0; mf < 2; ++mf) {
    int row = m0 + wr * 32 + mf * 16 + (lane & 15);
    int d1 = cnt1[row]; d1 = (d1 > CAP) ? CAP : d1;
    int d2 = cnt2[row]; d2 = (d2 > CAP) ? CAP : d2;
    dga[mf] = (float)d1;
    dgb[mf] = (float)d2;
  }

  f32x4 acc[2][4];
  #pragma unroll
  for (int i = 0; i < 2; ++i)
    #pragma unroll
    for (int j = 0; j < 4; ++j) acc[i][j] = {0.f, 0.f, 0.f, 0.f};

  for (int kt = 0; kt < 14; ++kt) {
    const unsigned short* aptr; int astride, kloc;
    if (kt < 2)      { aptr = xb; astride = 128; kloc = kt * 64; }
    else if (kt < 8) { aptr = s1; astride = 384; kloc = (kt - 2) * 64; }
    else             { aptr = s2; astride = 384; kloc = (kt - 8) * 64; }
    bool extra = (kt == 2) | (kt == 3) | (kt == 8) | (kt == 9);
    int base2 = (kt == 2) ? 896 : (kt == 3) ? 960 : (kt == 8) ? 1024 : 1088;

    #pragma unroll
    for (int i = 0; i < 2; ++i) {                 // A: 512 x 16B chunks
      int chunk = i * 256 + t;
      int r = chunk >> 3, c8 = chunk & 7;
      int c8s = c8 ^ (r & 7);                     // pre-swizzled source column
      gload16(As + chunk * 8, aptr + (size_t)(m0 + r) * astride + kloc + c8s * 8);
    }
    #pragma unroll
    for (int i = 0; i < 4; ++i) {                 // B: 1024 x 16B chunks
      int chunk = i * 256 + t;
      int r = chunk >> 3, c8 = chunk & 7;
      int c8s = c8 ^ (r & 7);
      gload16(Bs + chunk * 8, Bm + (size_t)r * 1152 + kt * 64 + c8s * 8);
      if (extra)
        gload16(Bs2 + chunk * 8, Bm + (size_t)r * 1152 + base2 + c8s * 8);
    }
    __syncthreads();

    #pragma unroll
    for (int kk = 0; kk < 2; ++kk) {
      bf16x8 a[2], b[4];
      int ccb = kk * 4 + (lane >> 4);             // chunk-column base (0..7)
      #pragma unroll
      for (int mf = 0; mf < 2; ++mf) {
        int row = wr * 32 + mf * 16 + (lane & 15);
        int swz = ccb ^ (row & 7);                // swizzled read
        a[mf] = *(const bf16x8*)(As + row * 64 + swz * 8);
      }
      #pragma unroll
      for (int nf = 0; nf < 4; ++nf) {
        int n = wc * 64 + nf * 16 + (lane & 15);
        int swz = ccb ^ (n & 7);
        b[nf] = *(const bf16x8*)(Bs + n * 64 + swz * 8);
      }
      #pragma unroll
      for (int mf = 0; mf < 2; ++mf)
        #pragma unroll
        for (int nf = 0; nf < 4; ++nf)
          acc[mf][nf] = __builtin_amdgcn_mfma_f32_16x16x32_bf16(a[mf], b[nf], acc[mf][nf], 0, 0, 0);

      if (extra) {                                // deg-fold: a*deg vs sum weights
        bf16x8 b2[4];
        #pragma unroll
        for (int nf = 0; nf < 4; ++nf) {
          int n = wc * 64 + nf * 16 + (lane & 15);
          int swz = ccb ^ (n & 7);
          b2[nf] = *(const bf16x8*)(Bs2 + n * 64 + swz * 8);
        }
        #pragma unroll
        for (int mf = 0; mf < 2; ++mf) {
          float dg = (kt < 8) ? dga[mf] : dgb[mf];
          bf16x8 as_;
          #pragma unroll
          for (int j = 0; j < 8; ++j) as_[j] = (__bf16)((float)a[mf][j] * dg);
          #pragma unroll
          for (int nf = 0; nf < 4; ++nf)
            acc[mf][nf] = __builtin_amdgcn_mfma_f32_16x16x32_bf16(as_, b2[nf], acc[mf][nf], 0, 0, 0);
        }
      }
    }
    __syncthreads();
  }

  // epilogue: h = relu(0.5*acc); LayerNorm over 128 cols per row
  float g[4], bta[4];
  #pragma unroll
  for (int nf = 0; nf < 4; ++nf) {
    int n = wc * 64 + nf * 16 + (lane & 15);
    g[nf] = gamma[n]; bta[nf] = beta[n];
  }

  #pragma unroll
  for (int mf = 0; mf < 2; ++mf) {
    #pragma unroll
    for (int r = 0; r < 4; ++r) {
      float ps = 0.f, pq = 0.f;
      #pragma unroll
      for (int nf = 0; nf < 4; ++nf) {
        float v = fmaxf(0.5f * acc[mf][nf][r], 0.0f);
        acc[mf][nf][r] = v;
        ps += v; pq += v * v;
      }
      #pragma unroll
      for (int d = 1; d < 16; d <<= 1) {
        ps += __shfl_xor(ps, d);
        pq += __shfl_xor(pq, d);
      }
      if ((lane & 15) == 0) {
        int m = wr * 32 + mf * 16 + ((lane >> 4) << 2) + r;
        rsum[m][wc] = ps;
        rsq[m][wc] = pq;
      }
    }
  }
  __syncthreads();

  #pragma unroll
  for (int mf = 0; mf < 2; ++mf) {
    #pragma unroll
    for (int r = 0; r < 4; ++r) {
      int m = wr * 32 + mf * 16 + ((lane >> 4) << 2) + r;
      float sum = rsum[m][0] + rsum[m][1];
      float sq  = rsq[m][0] + rsq[m][1];
      float mu = sum * (1.0f / 128.0f);
      float var = fmaxf(sq * (1.0f / 128.0f) - mu * mu, 0.0f);
      float rstd = rsqrtf(var + 1e-5f);
      int mg = m0 + m;
      if (mg < N_NODES) {
        #pragma unroll
        for (int nf = 0; nf < 4; ++nf) {
          int n = wc * 64 + nf * 16 + (lane & 15);
          out[(size_t)mg * 128 + n] = (acc[mf][nf][r] - mu) * rstd * g[nf] + bta[nf];
        }
      }
    }
  }
}

extern "C" void kernel_launch(void* const* d_in, const int* in_sizes, int n_in,
                              void* d_out, int out_size, void* d_ws, size_t ws_size,
                              hipStream_t stream) {
  const float* x    = (const float*)d_in[0];
  const int*   ei1  = (const int*)d_in[1];
  const int*   ei2  = (const int*)d_in[2];
  const float* W1a  = (const float*)d_in[3];
  const float* W2a  = (const float*)d_in[4];
  const float* W1b  = (const float*)d_in[5];
  const float* W2b  = (const float*)d_in[6];
  const float* gamma = (const float*)d_in[7];
  const float* beta  = (const float*)d_in[8];
  float* out = (float*)d_out;

  char* w = (char*)d_ws;
  auto alloc = [&](size_t b) { char* p = w; w += (b + 255) & ~(size_t)255; return p; };
  int* cnt1 = (int*)alloc((size_t)N_NODES * 4);
  int* cnt2 = (int*)alloc((size_t)N_NODES * 4);
  unsigned short* xb = (unsigned short*)alloc((size_t)M_PAD * 128 * 2);
  unsigned short* s1 = (unsigned short*)alloc((size_t)M_PAD * 384 * 2);
  unsigned short* s2 = (unsigned short*)alloc((size_t)M_PAD * 384 * 2);
  unsigned short* Bm = (unsigned short*)alloc((size_t)128 * 1152 * 2);

  // CSR slot arrays live in d_out: 2 * 50000*48*2B = 9.6MB << 25.6MB out buffer.
  unsigned short* csr1 = (unsigned short*)d_out;
  unsigned short* csr2 = csr1 + (size_t)N_NODES * CAP;

  hipMemsetAsync(cnt1, 0, (size_t)2 * N_NODES * 4 + 256, stream);
  phase1_kernel<<<11514, 256, 0, stream>>>(ei1, ei2, cnt1, cnt2, csr1, csr2,
                                           x, xb, W1a, W2a, W1b, W2b, Bm);
  aggregate_kernel<<<dim3(12500, 2), 256, 0, stream>>>(xb, csr1, cnt1, s1, csr2, cnt2, s2);
  gemm_ln_kernel<<<782, 256, 0, stream>>>(xb, s1, s2, Bm, cnt1, cnt2, gamma, beta, out);
}